// Round 10
// baseline (339.610 us; speedup 1.0000x reference)
//
#include <hip/hip_runtime.h>
#include <hip/hip_cooperative_groups.h>
#include <math.h>

namespace cg = cooperative_groups;

// B,S,E,H = 4,2048,1024,128
#define BB 4
#define SS 2048
#define EE 1024
#define HH 128
#define PLANE (BB * SS * HH)
#define BPLANE (SS * HH)
#define UPB_C 187          // coop: units/batch, 192-k chunks: sum ceil((t+1)/3)
#define NU_C (UPB_C * 4)   // 748
#define NBLK_MAX 768
#define AUNITS 272         // fallback: units/batch, 128-k chunks

typedef __bf16 bf16x8 __attribute__((ext_vector_type(8)));
typedef __bf16 bf16x4 __attribute__((ext_vector_type(4)));
typedef float f32x4 __attribute__((ext_vector_type(4)));

#define QSCALE (0.08838834764831845f * 1.4426950408889634f)  // 1/sqrt(H)*log2e

// ===========================================================================
// COOPERATIVE single-kernel path: nblk (grid-adaptive) x 256 thr, 4 phases.
// Every phase is a gridDim.x-strided loop, so any co-resident block count is
// correct; host launches min(768, occupancy-API bound). Bodies verbatim R9.
// ===========================================================================
__global__ __launch_bounds__(256, 2) void fused_head(
    const float* __restrict__ x, const float* __restrict__ Wq,
    const float* __restrict__ Wk, const float* __restrict__ Wv,
    __bf16* __restrict__ qkv, __bf16* __restrict__ WT,
    __bf16* __restrict__ Opart, float* __restrict__ lpart,
    float* __restrict__ out) {
  cg::grid_group grid = cg::this_grid();
  __shared__ __align__(16) char smem[35840];

  const int t = threadIdx.x, w = t >> 6, lane = t & 63;
  const int quad = lane >> 4, l16 = lane & 15;
  const int u = blockIdx.x;
  const int nb = gridDim.x;

  // ======================= Phase 0: W transpose (384 units) ==============
  for (int uu = u; uu < 384; uu += nb) {
    float* LT = (float*)smem;  // 32 x 33 fp32
    const int p = uu >> 7;
    const int r0 = uu & 127;
    const int kb = (r0 >> 2) * 32, nbo = (r0 & 3) * 32;
    const float* __restrict__ W = (p == 0) ? Wq : (p == 1) ? Wk : Wv;
    const int kr = t >> 3, nc4 = (t & 7) * 4;
    const float4 v = *(const float4*)&W[(size_t)(kb + kr) * HH + nbo + nc4];
    LT[(nc4 + 0) * 33 + kr] = v.x;
    LT[(nc4 + 1) * 33 + kr] = v.y;
    LT[(nc4 + 2) * 33 + kr] = v.z;
    LT[(nc4 + 3) * 33 + kr] = v.w;
    __syncthreads();
    const int n = t >> 3, kc = (t & 7) * 4;
    bf16x4 o;
#pragma unroll
    for (int i = 0; i < 4; ++i) o[i] = (__bf16)LT[n * 33 + kc + i];
    *(bf16x4*)&WT[(size_t)p * (HH * EE) + (size_t)(nbo + n) * EE + kb + kc] = o;
    __syncthreads();
  }
  __threadfence();
  grid.sync();

  // ======================= Phase 1: QKV projection (768 units) ===========
  for (int uu = u; uu < 768; uu += nb) {
    __bf16* xs = (__bf16*)smem;            // 32 rows x 64 k (stride 72)
    __bf16* wsd = (__bf16*)(smem + 4608);  // 128 n x 64 k (stride 72)
    const int mb = (uu & 255) * 32;
    const int proj = uu >> 8;
    const __bf16* __restrict__ WTp = WT + (size_t)proj * (HH * EE);

    const int xrow0 = t >> 4, xkc0 = (t & 15) * 4;
    const int wn0 = t >> 3, wkc0 = (t & 7) * 8;

    f32x4 acc[2][2];
#pragma unroll
    for (int i = 0; i < 2; ++i)
#pragma unroll
      for (int j = 0; j < 2; ++j) acc[i][j] = (f32x4){0.f, 0.f, 0.f, 0.f};

    float4 xr[2];
    bf16x8 wr[4];
#pragma unroll
    for (int i = 0; i < 2; ++i)
      xr[i] = *(const float4*)&x[(size_t)(mb + xrow0 + i * 16) * EE + xkc0];
#pragma unroll
    for (int i = 0; i < 4; ++i)
      wr[i] = *(const bf16x8*)&WTp[(size_t)(wn0 + i * 32) * EE + wkc0];

    for (int kt = 0; kt < 16; ++kt) {
      __syncthreads();
#pragma unroll
      for (int i = 0; i < 2; ++i) {
        bf16x4 bv;
        bv[0] = (__bf16)xr[i].x; bv[1] = (__bf16)xr[i].y;
        bv[2] = (__bf16)xr[i].z; bv[3] = (__bf16)xr[i].w;
        *(bf16x4*)&xs[(xrow0 + i * 16) * 72 + xkc0] = bv;
      }
#pragma unroll
      for (int i = 0; i < 4; ++i)
        *(bf16x8*)&wsd[(wn0 + i * 32) * 72 + wkc0] = wr[i];
      __syncthreads();

      if (kt < 15) {
        const int kb = (kt + 1) * 64;
#pragma unroll
        for (int i = 0; i < 2; ++i)
          xr[i] = *(const float4*)&x[(size_t)(mb + xrow0 + i * 16) * EE + kb + xkc0];
#pragma unroll
        for (int i = 0; i < 4; ++i)
          wr[i] = *(const bf16x8*)&WTp[(size_t)(wn0 + i * 32) * EE + kb + wkc0];
      }

      bf16x8 af[2][2], bfr[2][2];
#pragma unroll
      for (int mi = 0; mi < 2; ++mi)
#pragma unroll
        for (int kc = 0; kc < 2; ++kc)
          af[mi][kc] = *(const bf16x8*)&xs[(mi * 16 + l16) * 72 + kc * 32 + quad * 8];
#pragma unroll
      for (int ni = 0; ni < 2; ++ni)
#pragma unroll
        for (int kc = 0; kc < 2; ++kc)
          bfr[ni][kc] =
              *(const bf16x8*)&wsd[(w * 32 + ni * 16 + l16) * 72 + kc * 32 + quad * 8];
#pragma unroll
      for (int kc = 0; kc < 2; ++kc)
#pragma unroll
        for (int mi = 0; mi < 2; ++mi)
#pragma unroll
          for (int ni = 0; ni < 2; ++ni)
            acc[mi][ni] = __builtin_amdgcn_mfma_f32_16x16x32_bf16(
                af[mi][kc], bfr[ni][kc], acc[mi][ni], 0, 0, 0);
    }

    if (proj < 2) {
      const float scale = (proj == 0) ? QSCALE : 1.0f;
      __bf16* outp = qkv + (size_t)proj * PLANE;
#pragma unroll
      for (int mi = 0; mi < 2; ++mi) {
        const int srow = mb + mi * 16 + quad * 4;
#pragma unroll
        for (int ni = 0; ni < 2; ++ni) {
          const int col = w * 32 + ni * 16 + l16;
#pragma unroll
          for (int rr = 0; rr < 4; ++rr)
            outp[(size_t)(srow + rr) * HH + col] = (__bf16)(acc[mi][ni][rr] * scale);
        }
      }
    } else {
      __bf16* vtp = qkv + 2 * (size_t)PLANE;
#pragma unroll
      for (int mi = 0; mi < 2; ++mi) {
        const int srow = mb + mi * 16 + quad * 4;
        const int bb2 = srow >> 11, sl = srow & 2047;
#pragma unroll
        for (int ni = 0; ni < 2; ++ni) {
          const int d = w * 32 + ni * 16 + l16;
          bf16x4 vv;
#pragma unroll
          for (int rr = 0; rr < 4; ++rr) vv[rr] = (__bf16)acc[mi][ni][rr];
          *(bf16x4*)&vtp[(size_t)bb2 * BPLANE + (size_t)d * SS + sl] = vv;
        }
      }
    }
    __syncthreads();
  }
  __threadfence();
  grid.sync();

  // ======================= Phase 2: causal attention (748 units) =========
  for (int uu = u; uu < NU_C; uu += nb) {
    __bf16* K_s = (__bf16*)smem;             // 64 x 136
    __bf16* VT_s = (__bf16*)(smem + 17408);  // 128 x 72
    const int ur = (NU_C - 1) - uu;  // heavy-first
    const int b = ur & 3;
    const int r = ur >> 2;  // 0..186
    int tt = 0, Pp = 0;
    for (;;) {
      const int n = (tt + 3) / 3;  // chunks for tile tt
      if (r < Pp + n) break;
      Pp += n;
      ++tt;
    }
    const int c = r - Pp;
    const int qrb = tt * 64;
    const int k0 = c * 192;
    const int kend = min(k0 + 192, qrb + 64);
    const int ntiles = (kend - k0 + 63) >> 6;  // 1..3
    const int qsb = qrb + w * 16;

    const size_t bq = (size_t)b * BPLANE;
    const __bf16* __restrict__ qp = qkv + bq;
    const __bf16* __restrict__ kp = qkv + PLANE + bq;
    const __bf16* __restrict__ vt = qkv + 2 * (size_t)PLANE + bq;  // [d][s]

    bf16x8 qf[4];
#pragma unroll
    for (int cc = 0; cc < 4; ++cc)
      qf[cc] = *(const bf16x8*)&qp[(size_t)(qsb + l16) * HH + cc * 32 + quad * 8];

    f32x4 of[8];
#pragma unroll
    for (int f = 0; f < 8; ++f) of[f] = (f32x4){0.f, 0.f, 0.f, 0.f};
    float lp = 0.f;  // per lane: q = qsb + l16

    bf16x8 krg[4], vrg[4];
#pragma unroll
    for (int i = 0; i < 4; ++i) {
      const int idx = t + i * 256;
      const int row = idx >> 4, dc = (idx & 15) * 8;
      krg[i] = *(const bf16x8*)&kp[(size_t)(k0 + row) * HH + dc];
    }
#pragma unroll
    for (int i = 0; i < 4; ++i) {
      const int idx = t + i * 256;
      const int d = idx >> 3, kc = (idx & 7) * 8;
      vrg[i] = *(const bf16x8*)&vt[(size_t)d * SS + k0 + kc];
    }

    for (int jt = 0; jt < ntiles; ++jt) {
      __syncthreads();
#pragma unroll
      for (int i = 0; i < 4; ++i) {
        const int idx = t + i * 256;
        const int row = idx >> 4, dc = (idx & 15) * 8;
        const int lam = (row & 32) + ((row & 4) ? 16 : 0) +
                        (((row & 31) >> 3) << 2) + (row & 3);
        *(bf16x8*)&K_s[lam * 136 + dc] = krg[i];
      }
#pragma unroll
      for (int i = 0; i < 4; ++i) {
        const int idx = t + i * 256;
        const int d = idx >> 3, kc = (idx & 7) * 8;
        *(bf16x8*)&VT_s[d * 72 + kc] = vrg[i];
      }
      __syncthreads();

      if (jt + 1 < ntiles) {
        const int kb2 = k0 + (jt + 1) * 64;
#pragma unroll
        for (int i = 0; i < 4; ++i) {
          const int idx = t + i * 256;
          const int row = idx >> 4, dc = (idx & 15) * 8;
          krg[i] = *(const bf16x8*)&kp[(size_t)(kb2 + row) * HH + dc];
        }
#pragma unroll
        for (int i = 0; i < 4; ++i) {
          const int idx = t + i * 256;
          const int d = idx >> 3, kc = (idx & 7) * 8;
          vrg[i] = *(const bf16x8*)&vt[(size_t)d * SS + kb2 + kc];
        }
      }

#pragma unroll
      for (int s32 = 0; s32 < 2; ++s32) {
        const int kabs = k0 + jt * 64 + s32 * 32;
        if (kabs <= qsb + 15) {  // wave-uniform skip of fully-masked steps
          bf16x8 ku[4], kv[4];
#pragma unroll
          for (int cc = 0; cc < 4; ++cc) {
            ku[cc] = *(const bf16x8*)&K_s[(s32 * 32 + l16) * 136 + cc * 32 + quad * 8];
            kv[cc] = *(const bf16x8*)&K_s[(s32 * 32 + 16 + l16) * 136 + cc * 32 + quad * 8];
          }
          f32x4 su = (f32x4){0.f, 0.f, 0.f, 0.f};
          f32x4 sv = (f32x4){0.f, 0.f, 0.f, 0.f};
#pragma unroll
          for (int cc = 0; cc < 4; ++cc) {
            su = __builtin_amdgcn_mfma_f32_16x16x32_bf16(ku[cc], qf[cc], su, 0, 0, 0);
            sv = __builtin_amdgcn_mfma_f32_16x16x32_bf16(kv[cc], qf[cc], sv, 0, 0, 0);
          }
          const int qg = qsb + l16;
          bf16x8 pa;
#pragma unroll
          for (int rr = 0; rr < 4; ++rr) {
            const int kU = kabs + quad * 8 + rr;
            const float eU = (kU <= qg) ? exp2f(su[rr]) : 0.f;
            const float eV = (kU + 4 <= qg) ? exp2f(sv[rr]) : 0.f;
            pa[rr] = (__bf16)eU;
            pa[4 + rr] = (__bf16)eV;
            lp += eU + eV;
          }
#pragma unroll
          for (int f = 0; f < 8; ++f) {
            const bf16x8 vb =
                *(const bf16x8*)&VT_s[(f * 16 + l16) * 72 + s32 * 32 + quad * 8];
            of[f] = __builtin_amdgcn_mfma_f32_16x16x32_bf16(pa, vb, of[f], 0, 0, 0);
          }
        }
      }
    }

    lp += __shfl_xor(lp, 16);
    lp += __shfl_xor(lp, 32);

    if (tt < 3) {  // single chunk: finalize directly
#pragma unroll
      for (int rr = 0; rr < 4; ++rr) {
        const float lrow = __shfl(lp, quad * 4 + rr);
        const float inv = 1.0f / lrow;
#pragma unroll
        for (int f = 0; f < 8; ++f)
          out[bq + (size_t)(qsb + quad * 4 + rr) * HH + f * 16 + l16] =
              of[f][rr] * inv;
      }
    } else {
      const int us = b * UPB_C + r;
      __bf16* op = Opart + (size_t)us * 8192;
#pragma unroll
      for (int f = 0; f < 8; ++f)
#pragma unroll
        for (int rr = 0; rr < 4; ++rr)
          op[(w * 16 + quad * 4 + rr) * 128 + f * 16 + l16] = (__bf16)of[f][rr];
      if (quad == 0) lpart[us * 64 + w * 16 + l16] = lp;
    }
    __syncthreads();
  }
  __threadfence();
  grid.sync();

  // ======================= Phase 3: merge (464 units) ====================
  for (int uu = u; uu < 464; uu += nb) {
    const int q4 = uu & 3;
    const int m = uu >> 2;  // 0..115
    const int b = m / 29;
    const int tile = 3 + (m % 29);
    const int nc = (tile + 3) / 3;
    int Pp = 0;
    for (int j = 0; j < tile; ++j) Pp += (j + 3) / 3;
    const int u0 = b * UPB_C + Pp;
    const int idx = q4 * 256 + t;
    const int e0 = idx * 8;
    const int row = idx >> 4;
    float acc[8] = {0.f, 0.f, 0.f, 0.f, 0.f, 0.f, 0.f, 0.f};
    float lsum = 0.f;
    for (int cc = 0; cc < nc; ++cc) {
      const bf16x8 pv = *(const bf16x8*)&Opart[(size_t)(u0 + cc) * 8192 + e0];
#pragma unroll
      for (int k = 0; k < 8; ++k) acc[k] += (float)pv[k];
      lsum += lpart[(u0 + cc) * 64 + row];
    }
    const float inv = 1.0f / lsum;
    float4 r0, r1;
    r0.x = acc[0] * inv; r0.y = acc[1] * inv; r0.z = acc[2] * inv; r0.w = acc[3] * inv;
    r1.x = acc[4] * inv; r1.y = acc[5] * inv; r1.z = acc[6] * inv; r1.w = acc[7] * inv;
    float* op = out + (size_t)b * BPLANE + (size_t)tile * 8192 + e0;
    ((float4*)op)[0] = r0;
    ((float4*)op)[1] = r1;
  }
}

// ===========================================================================
// FALLBACK path: the R7-verified 4-kernel pipeline (unchanged).
// ===========================================================================
__global__ __launch_bounds__(256) void prep_w(
    const float* __restrict__ Wq, const float* __restrict__ Wk,
    const float* __restrict__ Wv, __bf16* __restrict__ WT) {
  __shared__ float LT[32 * 33];
  const int p = blockIdx.x >> 7;
  const int r = blockIdx.x & 127;
  const int kb = (r >> 2) * 32, nb = (r & 3) * 32;
  const float* __restrict__ W = (p == 0) ? Wq : (p == 1) ? Wk : Wv;
  const int t = threadIdx.x;
  const int kr = t >> 3, nc4 = (t & 7) * 4;
  const float4 v = *(const float4*)&W[(size_t)(kb + kr) * HH + nb + nc4];
  LT[(nc4 + 0) * 33 + kr] = v.x;
  LT[(nc4 + 1) * 33 + kr] = v.y;
  LT[(nc4 + 2) * 33 + kr] = v.z;
  LT[(nc4 + 3) * 33 + kr] = v.w;
  __syncthreads();
  const int n = t >> 3, kc = (t & 7) * 4;
  bf16x4 o;
#pragma unroll
  for (int i = 0; i < 4; ++i) o[i] = (__bf16)LT[n * 33 + kc + i];
  *(bf16x4*)&WT[(size_t)p * (HH * EE) + (size_t)(nb + n) * EE + kb + kc] = o;
}

__global__ __launch_bounds__(256, 4) void qkv_proj(
    const float* __restrict__ x, const __bf16* __restrict__ WT,
    __bf16* __restrict__ qkv) {
  __shared__ __align__(16) __bf16 xs[32 * 72];
  __shared__ __align__(16) __bf16 wsd[128 * 72];

  const int t = threadIdx.x, w = t >> 6, lane = t & 63;
  const int quad = lane >> 4, l16 = lane & 15;
  const int mb = blockIdx.x * 32;
  const int proj = blockIdx.y;
  const __bf16* __restrict__ WTp = WT + (size_t)proj * (HH * EE);

  const int xrow0 = t >> 4, xkc0 = (t & 15) * 4;
  const int wn0 = t >> 3, wkc0 = (t & 7) * 8;

  f32x4 acc[2][2];
#pragma unroll
  for (int i = 0; i < 2; ++i)
#pragma unroll
    for (int j = 0; j < 2; ++j) acc[i][j] = (f32x4){0.f, 0.f, 0.f, 0.f};

  float4 xr[2];
  bf16x8 wr[4];
#pragma unroll
  for (int i = 0; i < 2; ++i)
    xr[i] = *(const float4*)&x[(size_t)(mb + xrow0 + i * 16) * EE + xkc0];
#pragma unroll
  for (int i = 0; i < 4; ++i)
    wr[i] = *(const bf16x8*)&WTp[(size_t)(wn0 + i * 32) * EE + wkc0];

  for (int kt = 0; kt < 16; ++kt) {
    __syncthreads();
#pragma unroll
    for (int i = 0; i < 2; ++i) {
      bf16x4 bv;
      bv[0] = (__bf16)xr[i].x; bv[1] = (__bf16)xr[i].y;
      bv[2] = (__bf16)xr[i].z; bv[3] = (__bf16)xr[i].w;
      *(bf16x4*)&xs[(xrow0 + i * 16) * 72 + xkc0] = bv;
    }
#pragma unroll
    for (int i = 0; i < 4; ++i)
      *(bf16x8*)&wsd[(wn0 + i * 32) * 72 + wkc0] = wr[i];
    __syncthreads();

    if (kt < 15) {
      const int kb = (kt + 1) * 64;
#pragma unroll
      for (int i = 0; i < 2; ++i)
        xr[i] = *(const float4*)&x[(size_t)(mb + xrow0 + i * 16) * EE + kb + xkc0];
#pragma unroll
      for (int i = 0; i < 4; ++i)
        wr[i] = *(const bf16x8*)&WTp[(size_t)(wn0 + i * 32) * EE + kb + wkc0];
    }

    bf16x8 af[2][2], bfr[2][2];
#pragma unroll
    for (int mi = 0; mi < 2; ++mi)
#pragma unroll
      for (int kc = 0; kc < 2; ++kc)
        af[mi][kc] = *(const bf16x8*)&xs[(mi * 16 + l16) * 72 + kc * 32 + quad * 8];
#pragma unroll
    for (int ni = 0; ni < 2; ++ni)
#pragma unroll
      for (int kc = 0; kc < 2; ++kc)
        bfr[ni][kc] =
            *(const bf16x8*)&wsd[(w * 32 + ni * 16 + l16) * 72 + kc * 32 + quad * 8];
#pragma unroll
    for (int kc = 0; kc < 2; ++kc)
#pragma unroll
      for (int mi = 0; mi < 2; ++mi)
#pragma unroll
        for (int ni = 0; ni < 2; ++ni)
          acc[mi][ni] = __builtin_amdgcn_mfma_f32_16x16x32_bf16(
              af[mi][kc], bfr[ni][kc], acc[mi][ni], 0, 0, 0);
  }

  if (proj < 2) {
    const float scale = (proj == 0) ? QSCALE : 1.0f;
    __bf16* outp = qkv + (size_t)proj * PLANE;
#pragma unroll
    for (int mi = 0; mi < 2; ++mi) {
      const int srow = mb + mi * 16 + quad * 4;
#pragma unroll
      for (int ni = 0; ni < 2; ++ni) {
        const int col = w * 32 + ni * 16 + l16;
#pragma unroll
        for (int rr = 0; rr < 4; ++rr)
          outp[(size_t)(srow + rr) * HH + col] = (__bf16)(acc[mi][ni][rr] * scale);
      }
    }
  } else {
    __bf16* vtp = qkv + 2 * (size_t)PLANE;
#pragma unroll
    for (int mi = 0; mi < 2; ++mi) {
      const int srow = mb + mi * 16 + quad * 4;
      const int bb2 = srow >> 11, sl = srow & 2047;
#pragma unroll
      for (int ni = 0; ni < 2; ++ni) {
        const int d = w * 32 + ni * 16 + l16;
        bf16x4 vv;
#pragma unroll
        for (int rr = 0; rr < 4; ++rr) vv[rr] = (__bf16)acc[mi][ni][rr];
        *(bf16x4*)&vtp[(size_t)bb2 * BPLANE + (size_t)d * SS + sl] = vv;
      }
    }
  }
}

__global__ __launch_bounds__(256, 3) void flash_attn_mfma(
    const __bf16* __restrict__ qkv, float* __restrict__ out,
    __bf16* __restrict__ Opart, float* __restrict__ lpart) {
  __shared__ __align__(16) __bf16 K_s[64 * 136];
  __shared__ __align__(16) __bf16 VT_s[128 * 72];

  const int t = threadIdx.x, w = t >> 6, lane = t & 63;
  const int quad = lane >> 4, l16 = lane & 15;
  const int b = blockIdx.x & 3;
  const int r = (AUNITS - 1) - (blockIdx.x >> 2);
  int tt = 0;
  while ((((tt + 2) * (tt + 2)) >> 2) <= r) ++tt;
  const int c = r - (((tt + 1) * (tt + 1)) >> 2);
  const int qrb = tt * 64;
  const int k0 = c * 128;
  const int kend = min(k0 + 128, qrb + 64);
  const int ntiles = (kend - k0) >> 6;
  const int qsb = qrb + w * 16;

  const size_t bq = (size_t)b * BPLANE;
  const __bf16* __restrict__ qp = qkv + bq;
  const __bf16* __restrict__ kp = qkv + PLANE + bq;
  const __bf16* __restrict__ vt = qkv + 2 * (size_t)PLANE + bq;

  bf16x8 qf[4];
#pragma unroll
  for (int cc = 0; cc < 4; ++cc)
    qf[cc] = *(const bf16x8*)&qp[(size_t)(qsb + l16) * HH + cc * 32 + quad * 8];

  f32x4 of[8];
#pragma unroll
  for (int f = 0; f < 8; ++f) of[f] = (f32x4){0.f, 0.f, 0.f, 0.f};
  float lp = 0.f;

  bf16x8 krg[4], vrg[4];
#pragma unroll
  for (int i = 0; i < 4; ++i) {
    const int idx = t + i * 256;
    const int row = idx >> 4, dc = (idx & 15) * 8;
    krg[i] = *(const bf16x8*)&kp[(size_t)(k0 + row) * HH + dc];
  }
#pragma unroll
  for (int i = 0; i < 4; ++i) {
    const int idx = t + i * 256;
    const int d = idx >> 3, kc = (idx & 7) * 8;
    vrg[i] = *(const bf16x8*)&vt[(size_t)d * SS + k0 + kc];
  }

  for (int jt = 0; jt < ntiles; ++jt) {
    __syncthreads();
#pragma unroll
    for (int i = 0; i < 4; ++i) {
      const int idx = t + i * 256;
      const int row = idx >> 4, dc = (idx & 15) * 8;
      const int lam = (row & 32) + ((row & 4) ? 16 : 0) +
                      (((row & 31) >> 3) << 2) + (row & 3);
      *(bf16x8*)&K_s[lam * 136 + dc] = krg[i];
    }
#pragma unroll
    for (int i = 0; i < 4; ++i) {
      const int idx = t + i * 256;
      const int d = idx >> 3, kc = (idx & 7) * 8;
      *(bf16x8*)&VT_s[d * 72 + kc] = vrg[i];
    }
    __syncthreads();

    if (jt + 1 < ntiles) {
      const int kb2 = k0 + (jt + 1) * 64;
#pragma unroll
      for (int i = 0; i < 4; ++i) {
        const int idx = t + i * 256;
        const int row = idx >> 4, dc = (idx & 15) * 8;
        krg[i] = *(const bf16x8*)&kp[(size_t)(kb2 + row) * HH + dc];
      }
#pragma unroll
      for (int i = 0; i < 4; ++i) {
        const int idx = t + i * 256;
        const int d = idx >> 3, kc = (idx & 7) * 8;
        vrg[i] = *(const bf16x8*)&vt[(size_t)d * SS + kb2 + kc];
      }
    }

#pragma unroll
    for (int s32 = 0; s32 < 2; ++s32) {
      const int kabs = k0 + jt * 64 + s32 * 32;
      if (kabs <= qsb + 15) {
        bf16x8 ku[4], kv[4];
#pragma unroll
        for (int cc = 0; cc < 4; ++cc) {
          ku[cc] = *(const bf16x8*)&K_s[(s32 * 32 + l16) * 136 + cc * 32 + quad * 8];
          kv[cc] = *(const bf16x8*)&K_s[(s32 * 32 + 16 + l16) * 136 + cc * 32 + quad * 8];
        }
        f32x4 su = (f32x4){0.f, 0.f, 0.f, 0.f};
        f32x4 sv = (f32x4){0.f, 0.f, 0.f, 0.f};
#pragma unroll
        for (int cc = 0; cc < 4; ++cc) {
          su = __builtin_amdgcn_mfma_f32_16x16x32_bf16(ku[cc], qf[cc], su, 0, 0, 0);
          sv = __builtin_amdgcn_mfma_f32_16x16x32_bf16(kv[cc], qf[cc], sv, 0, 0, 0);
        }
        const int qg = qsb + l16;
        bf16x8 pa;
#pragma unroll
        for (int rr = 0; rr < 4; ++rr) {
          const int kU = kabs + quad * 8 + rr;
          const float eU = (kU <= qg) ? exp2f(su[rr]) : 0.f;
          const float eV = (kU + 4 <= qg) ? exp2f(sv[rr]) : 0.f;
          pa[rr] = (__bf16)eU;
          pa[4 + rr] = (__bf16)eV;
          lp += eU + eV;
        }
#pragma unroll
        for (int f = 0; f < 8; ++f) {
          const bf16x8 vb =
              *(const bf16x8*)&VT_s[(f * 16 + l16) * 72 + s32 * 32 + quad * 8];
          of[f] = __builtin_amdgcn_mfma_f32_16x16x32_bf16(pa, vb, of[f], 0, 0, 0);
        }
      }
    }
  }

  lp += __shfl_xor(lp, 16);
  lp += __shfl_xor(lp, 32);

  if (tt < 2) {
#pragma unroll
    for (int rr = 0; rr < 4; ++rr) {
      const float lrow = __shfl(lp, quad * 4 + rr);
      const float inv = 1.0f / lrow;
#pragma unroll
      for (int f = 0; f < 8; ++f)
        out[bq + (size_t)(qsb + quad * 4 + rr) * HH + f * 16 + l16] =
            of[f][rr] * inv;
    }
  } else {
    const int u = b * AUNITS + r;
    __bf16* op = Opart + (size_t)u * 8192;
#pragma unroll
    for (int f = 0; f < 8; ++f)
#pragma unroll
      for (int rr = 0; rr < 4; ++rr)
        op[(w * 16 + quad * 4 + rr) * 128 + f * 16 + l16] = (__bf16)of[f][rr];
    if (quad == 0) lpart[u * 64 + w * 16 + l16] = lp;
  }
}

__global__ __launch_bounds__(256) void attn_merge(
    const __bf16* __restrict__ Opart, const float* __restrict__ lpart,
    float* __restrict__ out) {
  const int q4 = blockIdx.x & 3;
  const int m = blockIdx.x >> 2;  // 0..119
  const int b = m / 30;
  const int tile = 2 + (m % 30);
  const int nc = (tile + 2) >> 1;
  const int u0 = b * AUNITS + (((tile + 1) * (tile + 1)) >> 2);
  const int idx = q4 * 256 + threadIdx.x;
  const int e0 = idx * 8;
  const int row = idx >> 4;
  float acc[8] = {0.f, 0.f, 0.f, 0.f, 0.f, 0.f, 0.f, 0.f};
  float lsum = 0.f;
  for (int cc = 0; cc < nc; ++cc) {
    const bf16x8 pv = *(const bf16x8*)&Opart[(size_t)(u0 + cc) * 8192 + e0];
#pragma unroll
    for (int k = 0; k < 8; ++k) acc[k] += (float)pv[k];
    lsum += lpart[(u0 + cc) * 64 + row];
  }
  const float inv = 1.0f / lsum;
  float4 r0, r1;
  r0.x = acc[0] * inv; r0.y = acc[1] * inv; r0.z = acc[2] * inv; r0.w = acc[3] * inv;
  r1.x = acc[4] * inv; r1.y = acc[5] * inv; r1.z = acc[6] * inv; r1.w = acc[7] * inv;
  float* op = out + (size_t)b * BPLANE + (size_t)tile * 8192 + e0;
  ((float4*)op)[0] = r0;
  ((float4*)op)[1] = r1;
}

extern "C" void kernel_launch(void* const* d_in, const int* in_sizes, int n_in,
                              void* d_out, int out_size, void* d_ws, size_t ws_size,
                              hipStream_t stream) {
  const float* x  = (const float*)d_in[0];
  const float* Wq = (const float*)d_in[1];
  const float* Wk = (const float*)d_in[2];
  const float* Wv = (const float*)d_in[3];
  float* out = (float*)d_out;

  // ws: qkv bf16 6.29MB | WT 0.79MB | Opart (sized for fallback) 17.8MB | lpart
  char* wsb = (char*)d_ws;
  __bf16* qkv = (__bf16*)wsb;
  __bf16* WT = (__bf16*)(wsb + (size_t)3 * PLANE * 2);
  __bf16* Opart = (__bf16*)(wsb + (size_t)3 * PLANE * 2 + (size_t)3 * HH * EE * 2);
  float* lpart = (float*)(wsb + (size_t)3 * PLANE * 2 + (size_t)3 * HH * EE * 2 +
                          (size_t)BB * AUNITS * 8192 * 2);

  // Host-only queries (capture-safe): how many blocks can be co-resident?
  int dev = 0;
  (void)hipGetDevice(&dev);
  int coop = 0, ncu = 0, maxb = 0;
  (void)hipDeviceGetAttribute(&coop, hipDeviceAttributeCooperativeLaunch, dev);
  (void)hipDeviceGetAttribute(&ncu, hipDeviceAttributeMultiprocessorCount, dev);
  (void)hipOccupancyMaxActiveBlocksPerMultiprocessor(&maxb, (const void*)fused_head,
                                                     256, 0);
  long cap = (long)maxb * (long)ncu;
  int nblk = (int)((cap < NBLK_MAX) ? cap : NBLK_MAX);
  const bool use_coop = (coop != 0) && (nblk >= 256);

  if (use_coop) {
    void* args[] = {(void*)&x, (void*)&Wq, (void*)&Wk, (void*)&Wv,
                    (void*)&qkv, (void*)&WT, (void*)&Opart, (void*)&lpart,
                    (void*)&out};
    hipLaunchCooperativeKernel((void*)fused_head, dim3(nblk), dim3(256), args,
                               0, stream);
  } else {
    prep_w<<<384, 256, 0, stream>>>(Wq, Wk, Wv, WT);
    qkv_proj<<<dim3(BB * SS / 32, 3), 256, 0, stream>>>(x, WT, qkv);
    flash_attn_mfma<<<BB * AUNITS, 256, 0, stream>>>(qkv, out, Opart, lpart);
    attn_merge<<<BB * 30 * 4, 256, 0, stream>>>(Opart, lpart, out);
  }
}

// Round 11
// 115.632 us; speedup vs baseline: 2.9370x; 2.9370x over previous
//
#include <hip/hip_runtime.h>
#include <hip/hip_cooperative_groups.h>
#include <math.h>

namespace cg = cooperative_groups;

// B,S,E,H = 4,2048,1024,128
#define BB 4
#define SS 2048
#define EE 1024
#define HH 128
#define PLANE (BB * SS * HH)
#define BPLANE (SS * HH)
#define UPB_C 187          // coop: units/batch, 192-k chunks: sum ceil((t+1)/3)
#define NU_C (UPB_C * 4)   // 748
#define NBLK_C 512         // EMPIRICAL: 512 (2/CU) fast; 768 -> 3x slower (R10)
#define AUNITS 272         // fallback: units/batch, 128-k chunks

typedef __bf16 bf16x8 __attribute__((ext_vector_type(8)));
typedef __bf16 bf16x4 __attribute__((ext_vector_type(4)));
typedef float f32x4 __attribute__((ext_vector_type(4)));

#define QSCALE (0.08838834764831845f * 1.4426950408889634f)  // 1/sqrt(H)*log2e

// ===========================================================================
// COOPERATIVE single-kernel path: 512 blocks x 256 thr, 4 phases.
// P1 restructured to 1536 units (32 rows x 64 cols) = exactly 3 rounds on
// 512 blocks, zero idle. Other phases verbatim R9 (verified).
// ===========================================================================
__global__ __launch_bounds__(256, 2) void fused_head(
    const float* __restrict__ x, const float* __restrict__ Wq,
    const float* __restrict__ Wk, const float* __restrict__ Wv,
    __bf16* __restrict__ qkv, __bf16* __restrict__ WT,
    __bf16* __restrict__ Opart, float* __restrict__ lpart,
    float* __restrict__ out) {
  cg::grid_group grid = cg::this_grid();
  __shared__ __align__(16) char smem[35840];

  const int t = threadIdx.x, w = t >> 6, lane = t & 63;
  const int quad = lane >> 4, l16 = lane & 15;
  const int u = blockIdx.x;
  const int nb = gridDim.x;

  // ======================= Phase 0: W transpose (384 units) ==============
  for (int uu = u; uu < 384; uu += nb) {
    float* LT = (float*)smem;  // 32 x 33 fp32
    const int p = uu >> 7;
    const int r0 = uu & 127;
    const int kb = (r0 >> 2) * 32, nbo = (r0 & 3) * 32;
    const float* __restrict__ W = (p == 0) ? Wq : (p == 1) ? Wk : Wv;
    const int kr = t >> 3, nc4 = (t & 7) * 4;
    const float4 v = *(const float4*)&W[(size_t)(kb + kr) * HH + nbo + nc4];
    LT[(nc4 + 0) * 33 + kr] = v.x;
    LT[(nc4 + 1) * 33 + kr] = v.y;
    LT[(nc4 + 2) * 33 + kr] = v.z;
    LT[(nc4 + 3) * 33 + kr] = v.w;
    __syncthreads();
    const int n = t >> 3, kc = (t & 7) * 4;
    bf16x4 o;
#pragma unroll
    for (int i = 0; i < 4; ++i) o[i] = (__bf16)LT[n * 33 + kc + i];
    *(bf16x4*)&WT[(size_t)p * (HH * EE) + (size_t)(nbo + n) * EE + kb + kc] = o;
    __syncthreads();
  }
  __threadfence();
  grid.sync();

  // ========== Phase 1: QKV projection (1536 units, 3 exact rounds) =======
  {
    const int wm = (w >> 1) * 16, wn2 = (w & 1) * 32;
    for (int uu = u; uu < 1536; uu += nb) {
      __bf16* xs = (__bf16*)smem;            // 32 rows x 64 k (stride 72)
      __bf16* wsd = (__bf16*)(smem + 4608);  // 64 n x 64 k (stride 72)
      const int proj = uu / 512;
      const int rem = uu & 511;
      const int mb = (rem >> 1) * 32;
      const int ch = rem & 1;
      const __bf16* __restrict__ WTp =
          WT + (size_t)proj * (HH * EE) + (size_t)(ch * 64) * EE;

      const int xrow0 = t >> 4, xkc0 = (t & 15) * 4;

      f32x4 acc[2];
#pragma unroll
      for (int j = 0; j < 2; ++j) acc[j] = (f32x4){0.f, 0.f, 0.f, 0.f};

      float4 xr[2];
      bf16x8 wr[2];
#pragma unroll
      for (int i = 0; i < 2; ++i)
        xr[i] = *(const float4*)&x[(size_t)(mb + xrow0 + i * 16) * EE + xkc0];
#pragma unroll
      for (int i = 0; i < 2; ++i) {
        const int idx = t + i * 256;
        wr[i] = *(const bf16x8*)&WTp[(size_t)(idx >> 3) * EE + (idx & 7) * 8];
      }

      for (int kt = 0; kt < 16; ++kt) {
        __syncthreads();
#pragma unroll
        for (int i = 0; i < 2; ++i) {
          bf16x4 bv;
          bv[0] = (__bf16)xr[i].x; bv[1] = (__bf16)xr[i].y;
          bv[2] = (__bf16)xr[i].z; bv[3] = (__bf16)xr[i].w;
          *(bf16x4*)&xs[(xrow0 + i * 16) * 72 + xkc0] = bv;
        }
#pragma unroll
        for (int i = 0; i < 2; ++i) {
          const int idx = t + i * 256;
          *(bf16x8*)&wsd[(idx >> 3) * 72 + (idx & 7) * 8] = wr[i];
        }
        __syncthreads();

        if (kt < 15) {
          const int kb = (kt + 1) * 64;
#pragma unroll
          for (int i = 0; i < 2; ++i)
            xr[i] = *(const float4*)&x[(size_t)(mb + xrow0 + i * 16) * EE + kb + xkc0];
#pragma unroll
          for (int i = 0; i < 2; ++i) {
            const int idx = t + i * 256;
            wr[i] = *(const bf16x8*)&WTp[(size_t)(idx >> 3) * EE + kb + (idx & 7) * 8];
          }
        }

        bf16x8 af[2], bfr[2][2];
#pragma unroll
        for (int kc = 0; kc < 2; ++kc)
          af[kc] = *(const bf16x8*)&xs[(wm + l16) * 72 + kc * 32 + quad * 8];
#pragma unroll
        for (int ni = 0; ni < 2; ++ni)
#pragma unroll
          for (int kc = 0; kc < 2; ++kc)
            bfr[ni][kc] =
                *(const bf16x8*)&wsd[(wn2 + ni * 16 + l16) * 72 + kc * 32 + quad * 8];
#pragma unroll
        for (int kc = 0; kc < 2; ++kc)
#pragma unroll
          for (int ni = 0; ni < 2; ++ni)
            acc[ni] = __builtin_amdgcn_mfma_f32_16x16x32_bf16(
                af[kc], bfr[ni][kc], acc[ni], 0, 0, 0);
      }

      const int srow0 = mb + wm + quad * 4;
      if (proj < 2) {
        const float scale = (proj == 0) ? QSCALE : 1.0f;
        __bf16* outp = qkv + (size_t)proj * PLANE;
#pragma unroll
        for (int ni = 0; ni < 2; ++ni) {
          const int col = ch * 64 + wn2 + ni * 16 + l16;
#pragma unroll
          for (int rr = 0; rr < 4; ++rr)
            outp[(size_t)(srow0 + rr) * HH + col] = (__bf16)(acc[ni][rr] * scale);
        }
      } else {
        __bf16* vtp = qkv + 2 * (size_t)PLANE;
        const int bb2 = srow0 >> 11, sl = srow0 & 2047;
#pragma unroll
        for (int ni = 0; ni < 2; ++ni) {
          const int d = ch * 64 + wn2 + ni * 16 + l16;
          bf16x4 vv;
#pragma unroll
          for (int rr = 0; rr < 4; ++rr) vv[rr] = (__bf16)acc[ni][rr];
          *(bf16x4*)&vtp[(size_t)bb2 * BPLANE + (size_t)d * SS + sl] = vv;
        }
      }
      __syncthreads();
    }
  }
  __threadfence();
  grid.sync();

  // ======================= Phase 2: causal attention (748 units) =========
  for (int uu = u; uu < NU_C; uu += nb) {
    __bf16* K_s = (__bf16*)smem;             // 64 x 136
    __bf16* VT_s = (__bf16*)(smem + 17408);  // 128 x 72
    const int ur = (NU_C - 1) - uu;  // heavy-first
    const int b = ur & 3;
    const int r = ur >> 2;  // 0..186
    int tt = 0, Pp = 0;
    for (;;) {
      const int n = (tt + 3) / 3;  // chunks for tile tt
      if (r < Pp + n) break;
      Pp += n;
      ++tt;
    }
    const int c = r - Pp;
    const int qrb = tt * 64;
    const int k0 = c * 192;
    const int kend = min(k0 + 192, qrb + 64);
    const int ntiles = (kend - k0 + 63) >> 6;  // 1..3
    const int qsb = qrb + w * 16;

    const size_t bq = (size_t)b * BPLANE;
    const __bf16* __restrict__ qp = qkv + bq;
    const __bf16* __restrict__ kp = qkv + PLANE + bq;
    const __bf16* __restrict__ vt = qkv + 2 * (size_t)PLANE + bq;  // [d][s]

    bf16x8 qf[4];
#pragma unroll
    for (int cc = 0; cc < 4; ++cc)
      qf[cc] = *(const bf16x8*)&qp[(size_t)(qsb + l16) * HH + cc * 32 + quad * 8];

    f32x4 of[8];
#pragma unroll
    for (int f = 0; f < 8; ++f) of[f] = (f32x4){0.f, 0.f, 0.f, 0.f};
    float lp = 0.f;  // per lane: q = qsb + l16

    bf16x8 krg[4], vrg[4];
#pragma unroll
    for (int i = 0; i < 4; ++i) {
      const int idx = t + i * 256;
      const int row = idx >> 4, dc = (idx & 15) * 8;
      krg[i] = *(const bf16x8*)&kp[(size_t)(k0 + row) * HH + dc];
    }
#pragma unroll
    for (int i = 0; i < 4; ++i) {
      const int idx = t + i * 256;
      const int d = idx >> 3, kc = (idx & 7) * 8;
      vrg[i] = *(const bf16x8*)&vt[(size_t)d * SS + k0 + kc];
    }

    for (int jt = 0; jt < ntiles; ++jt) {
      __syncthreads();
#pragma unroll
      for (int i = 0; i < 4; ++i) {
        const int idx = t + i * 256;
        const int row = idx >> 4, dc = (idx & 15) * 8;
        const int lam = (row & 32) + ((row & 4) ? 16 : 0) +
                        (((row & 31) >> 3) << 2) + (row & 3);
        *(bf16x8*)&K_s[lam * 136 + dc] = krg[i];
      }
#pragma unroll
      for (int i = 0; i < 4; ++i) {
        const int idx = t + i * 256;
        const int d = idx >> 3, kc = (idx & 7) * 8;
        *(bf16x8*)&VT_s[d * 72 + kc] = vrg[i];
      }
      __syncthreads();

      if (jt + 1 < ntiles) {
        const int kb2 = k0 + (jt + 1) * 64;
#pragma unroll
        for (int i = 0; i < 4; ++i) {
          const int idx = t + i * 256;
          const int row = idx >> 4, dc = (idx & 15) * 8;
          krg[i] = *(const bf16x8*)&kp[(size_t)(kb2 + row) * HH + dc];
        }
#pragma unroll
        for (int i = 0; i < 4; ++i) {
          const int idx = t + i * 256;
          const int d = idx >> 3, kc = (idx & 7) * 8;
          vrg[i] = *(const bf16x8*)&vt[(size_t)d * SS + kb2 + kc];
        }
      }

#pragma unroll
      for (int s32 = 0; s32 < 2; ++s32) {
        const int kabs = k0 + jt * 64 + s32 * 32;
        if (kabs <= qsb + 15) {  // wave-uniform skip of fully-masked steps
          bf16x8 ku[4], kv[4];
#pragma unroll
          for (int cc = 0; cc < 4; ++cc) {
            ku[cc] = *(const bf16x8*)&K_s[(s32 * 32 + l16) * 136 + cc * 32 + quad * 8];
            kv[cc] = *(const bf16x8*)&K_s[(s32 * 32 + 16 + l16) * 136 + cc * 32 + quad * 8];
          }
          f32x4 su = (f32x4){0.f, 0.f, 0.f, 0.f};
          f32x4 sv = (f32x4){0.f, 0.f, 0.f, 0.f};
#pragma unroll
          for (int cc = 0; cc < 4; ++cc) {
            su = __builtin_amdgcn_mfma_f32_16x16x32_bf16(ku[cc], qf[cc], su, 0, 0, 0);
            sv = __builtin_amdgcn_mfma_f32_16x16x32_bf16(kv[cc], qf[cc], sv, 0, 0, 0);
          }
          const int qg = qsb + l16;
          bf16x8 pa;
#pragma unroll
          for (int rr = 0; rr < 4; ++rr) {
            const int kU = kabs + quad * 8 + rr;
            const float eU = (kU <= qg) ? exp2f(su[rr]) : 0.f;
            const float eV = (kU + 4 <= qg) ? exp2f(sv[rr]) : 0.f;
            pa[rr] = (__bf16)eU;
            pa[4 + rr] = (__bf16)eV;
            lp += eU + eV;
          }
#pragma unroll
          for (int f = 0; f < 8; ++f) {
            const bf16x8 vb =
                *(const bf16x8*)&VT_s[(f * 16 + l16) * 72 + s32 * 32 + quad * 8];
            of[f] = __builtin_amdgcn_mfma_f32_16x16x32_bf16(pa, vb, of[f], 0, 0, 0);
          }
        }
      }
    }

    lp += __shfl_xor(lp, 16);
    lp += __shfl_xor(lp, 32);

    if (tt < 3) {  // single chunk: finalize directly
#pragma unroll
      for (int rr = 0; rr < 4; ++rr) {
        const float lrow = __shfl(lp, quad * 4 + rr);
        const float inv = 1.0f / lrow;
#pragma unroll
        for (int f = 0; f < 8; ++f)
          out[bq + (size_t)(qsb + quad * 4 + rr) * HH + f * 16 + l16] =
              of[f][rr] * inv;
      }
    } else {
      const int us = b * UPB_C + r;
      __bf16* op = Opart + (size_t)us * 8192;
#pragma unroll
      for (int f = 0; f < 8; ++f)
#pragma unroll
        for (int rr = 0; rr < 4; ++rr)
          op[(w * 16 + quad * 4 + rr) * 128 + f * 16 + l16] = (__bf16)of[f][rr];
      if (quad == 0) lpart[us * 64 + w * 16 + l16] = lp;
    }
    __syncthreads();
  }
  __threadfence();
  grid.sync();

  // ======================= Phase 3: merge (464 units) ====================
  for (int uu = u; uu < 464; uu += nb) {
    const int q4 = uu & 3;
    const int m = uu >> 2;  // 0..115
    const int b = m / 29;
    const int tile = 3 + (m % 29);
    const int nc = (tile + 3) / 3;
    int Pp = 0;
    for (int j = 0; j < tile; ++j) Pp += (j + 3) / 3;
    const int u0 = b * UPB_C + Pp;
    const int idx = q4 * 256 + t;
    const int e0 = idx * 8;
    const int row = idx >> 4;
    float acc[8] = {0.f, 0.f, 0.f, 0.f, 0.f, 0.f, 0.f, 0.f};
    float lsum = 0.f;
    for (int cc = 0; cc < nc; ++cc) {
      const bf16x8 pv = *(const bf16x8*)&Opart[(size_t)(u0 + cc) * 8192 + e0];
#pragma unroll
      for (int k = 0; k < 8; ++k) acc[k] += (float)pv[k];
      lsum += lpart[(u0 + cc) * 64 + row];
    }
    const float inv = 1.0f / lsum;
    float4 r0, r1;
    r0.x = acc[0] * inv; r0.y = acc[1] * inv; r0.z = acc[2] * inv; r0.w = acc[3] * inv;
    r1.x = acc[4] * inv; r1.y = acc[5] * inv; r1.z = acc[6] * inv; r1.w = acc[7] * inv;
    float* op = out + (size_t)b * BPLANE + (size_t)tile * 8192 + e0;
    ((float4*)op)[0] = r0;
    ((float4*)op)[1] = r1;
  }
}

// ===========================================================================
// FALLBACK path: the R7-verified 4-kernel pipeline (unchanged).
// ===========================================================================
__global__ __launch_bounds__(256) void prep_w(
    const float* __restrict__ Wq, const float* __restrict__ Wk,
    const float* __restrict__ Wv, __bf16* __restrict__ WT) {
  __shared__ float LT[32 * 33];
  const int p = blockIdx.x >> 7;
  const int r = blockIdx.x & 127;
  const int kb = (r >> 2) * 32, nb = (r & 3) * 32;
  const float* __restrict__ W = (p == 0) ? Wq : (p == 1) ? Wk : Wv;
  const int t = threadIdx.x;
  const int kr = t >> 3, nc4 = (t & 7) * 4;
  const float4 v = *(const float4*)&W[(size_t)(kb + kr) * HH + nb + nc4];
  LT[(nc4 + 0) * 33 + kr] = v.x;
  LT[(nc4 + 1) * 33 + kr] = v.y;
  LT[(nc4 + 2) * 33 + kr] = v.z;
  LT[(nc4 + 3) * 33 + kr] = v.w;
  __syncthreads();
  const int n = t >> 3, kc = (t & 7) * 4;
  bf16x4 o;
#pragma unroll
  for (int i = 0; i < 4; ++i) o[i] = (__bf16)LT[n * 33 + kc + i];
  *(bf16x4*)&WT[(size_t)p * (HH * EE) + (size_t)(nb + n) * EE + kb + kc] = o;
}

__global__ __launch_bounds__(256, 4) void qkv_proj(
    const float* __restrict__ x, const __bf16* __restrict__ WT,
    __bf16* __restrict__ qkv) {
  __shared__ __align__(16) __bf16 xs[32 * 72];
  __shared__ __align__(16) __bf16 wsd[128 * 72];

  const int t = threadIdx.x, w = t >> 6, lane = t & 63;
  const int quad = lane >> 4, l16 = lane & 15;
  const int mb = blockIdx.x * 32;
  const int proj = blockIdx.y;
  const __bf16* __restrict__ WTp = WT + (size_t)proj * (HH * EE);

  const int xrow0 = t >> 4, xkc0 = (t & 15) * 4;
  const int wn0 = t >> 3, wkc0 = (t & 7) * 8;

  f32x4 acc[2][2];
#pragma unroll
  for (int i = 0; i < 2; ++i)
#pragma unroll
    for (int j = 0; j < 2; ++j) acc[i][j] = (f32x4){0.f, 0.f, 0.f, 0.f};

  float4 xr[2];
  bf16x8 wr[4];
#pragma unroll
  for (int i = 0; i < 2; ++i)
    xr[i] = *(const float4*)&x[(size_t)(mb + xrow0 + i * 16) * EE + xkc0];
#pragma unroll
  for (int i = 0; i < 4; ++i)
    wr[i] = *(const bf16x8*)&WTp[(size_t)(wn0 + i * 32) * EE + wkc0];

  for (int kt = 0; kt < 16; ++kt) {
    __syncthreads();
#pragma unroll
    for (int i = 0; i < 2; ++i) {
      bf16x4 bv;
      bv[0] = (__bf16)xr[i].x; bv[1] = (__bf16)xr[i].y;
      bv[2] = (__bf16)xr[i].z; bv[3] = (__bf16)xr[i].w;
      *(bf16x4*)&xs[(xrow0 + i * 16) * 72 + xkc0] = bv;
    }
#pragma unroll
    for (int i = 0; i < 4; ++i)
      *(bf16x8*)&wsd[(wn0 + i * 32) * 72 + wkc0] = wr[i];
    __syncthreads();

    if (kt < 15) {
      const int kb = (kt + 1) * 64;
#pragma unroll
      for (int i = 0; i < 2; ++i)
        xr[i] = *(const float4*)&x[(size_t)(mb + xrow0 + i * 16) * EE + kb + xkc0];
#pragma unroll
      for (int i = 0; i < 4; ++i)
        wr[i] = *(const bf16x8*)&WTp[(size_t)(wn0 + i * 32) * EE + kb + wkc0];
    }

    bf16x8 af[2][2], bfr[2][2];
#pragma unroll
    for (int mi = 0; mi < 2; ++mi)
#pragma unroll
      for (int kc = 0; kc < 2; ++kc)
        af[mi][kc] = *(const bf16x8*)&xs[(mi * 16 + l16) * 72 + kc * 32 + quad * 8];
#pragma unroll
    for (int ni = 0; ni < 2; ++ni)
#pragma unroll
      for (int kc = 0; kc < 2; ++kc)
        bfr[ni][kc] =
            *(const bf16x8*)&wsd[(w * 32 + ni * 16 + l16) * 72 + kc * 32 + quad * 8];
#pragma unroll
    for (int kc = 0; kc < 2; ++kc)
#pragma unroll
      for (int mi = 0; mi < 2; ++mi)
#pragma unroll
        for (int ni = 0; ni < 2; ++ni)
          acc[mi][ni] = __builtin_amdgcn_mfma_f32_16x16x32_bf16(
              af[mi][kc], bfr[ni][kc], acc[mi][ni], 0, 0, 0);
  }

  if (proj < 2) {
    const float scale = (proj == 0) ? QSCALE : 1.0f;
    __bf16* outp = qkv + (size_t)proj * PLANE;
#pragma unroll
    for (int mi = 0; mi < 2; ++mi) {
      const int srow = mb + mi * 16 + quad * 4;
#pragma unroll
      for (int ni = 0; ni < 2; ++ni) {
        const int col = w * 32 + ni * 16 + l16;
#pragma unroll
        for (int rr = 0; rr < 4; ++rr)
          outp[(size_t)(srow + rr) * HH + col] = (__bf16)(acc[mi][ni][rr] * scale);
      }
    }
  } else {
    __bf16* vtp = qkv + 2 * (size_t)PLANE;
#pragma unroll
    for (int mi = 0; mi < 2; ++mi) {
      const int srow = mb + mi * 16 + quad * 4;
      const int bb2 = srow >> 11, sl = srow & 2047;
#pragma unroll
      for (int ni = 0; ni < 2; ++ni) {
        const int d = w * 32 + ni * 16 + l16;
        bf16x4 vv;
#pragma unroll
        for (int rr = 0; rr < 4; ++rr) vv[rr] = (__bf16)acc[mi][ni][rr];
        *(bf16x4*)&vtp[(size_t)bb2 * BPLANE + (size_t)d * SS + sl] = vv;
      }
    }
  }
}

__global__ __launch_bounds__(256, 3) void flash_attn_mfma(
    const __bf16* __restrict__ qkv, float* __restrict__ out,
    __bf16* __restrict__ Opart, float* __restrict__ lpart) {
  __shared__ __align__(16) __bf16 K_s[64 * 136];
  __shared__ __align__(16) __bf16 VT_s[128 * 72];

  const int t = threadIdx.x, w = t >> 6, lane = t & 63;
  const int quad = lane >> 4, l16 = lane & 15;
  const int b = blockIdx.x & 3;
  const int r = (AUNITS - 1) - (blockIdx.x >> 2);
  int tt = 0;
  while ((((tt + 2) * (tt + 2)) >> 2) <= r) ++tt;
  const int c = r - (((tt + 1) * (tt + 1)) >> 2);
  const int qrb = tt * 64;
  const int k0 = c * 128;
  const int kend = min(k0 + 128, qrb + 64);
  const int ntiles = (kend - k0) >> 6;
  const int qsb = qrb + w * 16;

  const size_t bq = (size_t)b * BPLANE;
  const __bf16* __restrict__ qp = qkv + bq;
  const __bf16* __restrict__ kp = qkv + PLANE + bq;
  const __bf16* __restrict__ vt = qkv + 2 * (size_t)PLANE + bq;

  bf16x8 qf[4];
#pragma unroll
  for (int cc = 0; cc < 4; ++cc)
    qf[cc] = *(const bf16x8*)&qp[(size_t)(qsb + l16) * HH + cc * 32 + quad * 8];

  f32x4 of[8];
#pragma unroll
  for (int f = 0; f < 8; ++f) of[f] = (f32x4){0.f, 0.f, 0.f, 0.f};
  float lp = 0.f;

  bf16x8 krg[4], vrg[4];
#pragma unroll
  for (int i = 0; i < 4; ++i) {
    const int idx = t + i * 256;
    const int row = idx >> 4, dc = (idx & 15) * 8;
    krg[i] = *(const bf16x8*)&kp[(size_t)(k0 + row) * HH + dc];
  }
#pragma unroll
  for (int i = 0; i < 4; ++i) {
    const int idx = t + i * 256;
    const int d = idx >> 3, kc = (idx & 7) * 8;
    vrg[i] = *(const bf16x8*)&vt[(size_t)d * SS + k0 + kc];
  }

  for (int jt = 0; jt < ntiles; ++jt) {
    __syncthreads();
#pragma unroll
    for (int i = 0; i < 4; ++i) {
      const int idx = t + i * 256;
      const int row = idx >> 4, dc = (idx & 15) * 8;
      const int lam = (row & 32) + ((row & 4) ? 16 : 0) +
                      (((row & 31) >> 3) << 2) + (row & 3);
      *(bf16x8*)&K_s[lam * 136 + dc] = krg[i];
    }
#pragma unroll
    for (int i = 0; i < 4; ++i) {
      const int idx = t + i * 256;
      const int d = idx >> 3, kc = (idx & 7) * 8;
      *(bf16x8*)&VT_s[d * 72 + kc] = vrg[i];
    }
    __syncthreads();

    if (jt + 1 < ntiles) {
      const int kb2 = k0 + (jt + 1) * 64;
#pragma unroll
      for (int i = 0; i < 4; ++i) {
        const int idx = t + i * 256;
        const int row = idx >> 4, dc = (idx & 15) * 8;
        krg[i] = *(const bf16x8*)&kp[(size_t)(kb2 + row) * HH + dc];
      }
#pragma unroll
      for (int i = 0; i < 4; ++i) {
        const int idx = t + i * 256;
        const int d = idx >> 3, kc = (idx & 7) * 8;
        vrg[i] = *(const bf16x8*)&vt[(size_t)d * SS + kb2 + kc];
      }
    }

#pragma unroll
    for (int s32 = 0; s32 < 2; ++s32) {
      const int kabs = k0 + jt * 64 + s32 * 32;
      if (kabs <= qsb + 15) {
        bf16x8 ku[4], kv[4];
#pragma unroll
        for (int cc = 0; cc < 4; ++cc) {
          ku[cc] = *(const bf16x8*)&K_s[(s32 * 32 + l16) * 136 + cc * 32 + quad * 8];
          kv[cc] = *(const bf16x8*)&K_s[(s32 * 32 + 16 + l16) * 136 + cc * 32 + quad * 8];
        }
        f32x4 su = (f32x4){0.f, 0.f, 0.f, 0.f};
        f32x4 sv = (f32x4){0.f, 0.f, 0.f, 0.f};
#pragma unroll
        for (int cc = 0; cc < 4; ++cc) {
          su = __builtin_amdgcn_mfma_f32_16x16x32_bf16(ku[cc], qf[cc], su, 0, 0, 0);
          sv = __builtin_amdgcn_mfma_f32_16x16x32_bf16(kv[cc], qf[cc], sv, 0, 0, 0);
        }
        const int qg = qsb + l16;
        bf16x8 pa;
#pragma unroll
        for (int rr = 0; rr < 4; ++rr) {
          const int kU = kabs + quad * 8 + rr;
          const float eU = (kU <= qg) ? exp2f(su[rr]) : 0.f;
          const float eV = (kU + 4 <= qg) ? exp2f(sv[rr]) : 0.f;
          pa[rr] = (__bf16)eU;
          pa[4 + rr] = (__bf16)eV;
          lp += eU + eV;
        }
#pragma unroll
        for (int f = 0; f < 8; ++f) {
          const bf16x8 vb =
              *(const bf16x8*)&VT_s[(f * 16 + l16) * 72 + s32 * 32 + quad * 8];
          of[f] = __builtin_amdgcn_mfma_f32_16x16x32_bf16(pa, vb, of[f], 0, 0, 0);
        }
      }
    }
  }

  lp += __shfl_xor(lp, 16);
  lp += __shfl_xor(lp, 32);

  if (tt < 2) {
#pragma unroll
    for (int rr = 0; rr < 4; ++rr) {
      const float lrow = __shfl(lp, quad * 4 + rr);
      const float inv = 1.0f / lrow;
#pragma unroll
      for (int f = 0; f < 8; ++f)
        out[bq + (size_t)(qsb + quad * 4 + rr) * HH + f * 16 + l16] =
            of[f][rr] * inv;
    }
  } else {
    const int u = b * AUNITS + r;
    __bf16* op = Opart + (size_t)u * 8192;
#pragma unroll
    for (int f = 0; f < 8; ++f)
#pragma unroll
      for (int rr = 0; rr < 4; ++rr)
        op[(w * 16 + quad * 4 + rr) * 128 + f * 16 + l16] = (__bf16)of[f][rr];
    if (quad == 0) lpart[u * 64 + w * 16 + l16] = lp;
  }
}

__global__ __launch_bounds__(256) void attn_merge(
    const __bf16* __restrict__ Opart, const float* __restrict__ lpart,
    float* __restrict__ out) {
  const int q4 = blockIdx.x & 3;
  const int m = blockIdx.x >> 2;  // 0..119
  const int b = m / 30;
  const int tile = 2 + (m % 30);
  const int nc = (tile + 2) >> 1;
  const int u0 = b * AUNITS + (((tile + 1) * (tile + 1)) >> 2);
  const int idx = q4 * 256 + threadIdx.x;
  const int e0 = idx * 8;
  const int row = idx >> 4;
  float acc[8] = {0.f, 0.f, 0.f, 0.f, 0.f, 0.f, 0.f, 0.f};
  float lsum = 0.f;
  for (int cc = 0; cc < nc; ++cc) {
    const bf16x8 pv = *(const bf16x8*)&Opart[(size_t)(u0 + cc) * 8192 + e0];
#pragma unroll
    for (int k = 0; k < 8; ++k) acc[k] += (float)pv[k];
    lsum += lpart[(u0 + cc) * 64 + row];
  }
  const float inv = 1.0f / lsum;
  float4 r0, r1;
  r0.x = acc[0] * inv; r0.y = acc[1] * inv; r0.z = acc[2] * inv; r0.w = acc[3] * inv;
  r1.x = acc[4] * inv; r1.y = acc[5] * inv; r1.z = acc[6] * inv; r1.w = acc[7] * inv;
  float* op = out + (size_t)b * BPLANE + (size_t)tile * 8192 + e0;
  ((float4*)op)[0] = r0;
  ((float4*)op)[1] = r1;
}

extern "C" void kernel_launch(void* const* d_in, const int* in_sizes, int n_in,
                              void* d_out, int out_size, void* d_ws, size_t ws_size,
                              hipStream_t stream) {
  const float* x  = (const float*)d_in[0];
  const float* Wq = (const float*)d_in[1];
  const float* Wk = (const float*)d_in[2];
  const float* Wv = (const float*)d_in[3];
  float* out = (float*)d_out;

  // ws: qkv bf16 6.29MB | WT 0.79MB | Opart (sized for fallback) 17.8MB | lpart
  char* wsb = (char*)d_ws;
  __bf16* qkv = (__bf16*)wsb;
  __bf16* WT = (__bf16*)(wsb + (size_t)3 * PLANE * 2);
  __bf16* Opart = (__bf16*)(wsb + (size_t)3 * PLANE * 2 + (size_t)3 * HH * EE * 2);
  float* lpart = (float*)(wsb + (size_t)3 * PLANE * 2 + (size_t)3 * HH * EE * 2 +
                          (size_t)BB * AUNITS * 8192 * 2);

  // Host-only queries (capture-safe). R10 lesson: do NOT exceed 512 blocks —
  // the occupancy API overstates coop co-residency (768 was 3x slower).
  int dev = 0;
  (void)hipGetDevice(&dev);
  int coop = 0, ncu = 0, maxb = 0;
  (void)hipDeviceGetAttribute(&coop, hipDeviceAttributeCooperativeLaunch, dev);
  (void)hipDeviceGetAttribute(&ncu, hipDeviceAttributeMultiprocessorCount, dev);
  (void)hipOccupancyMaxActiveBlocksPerMultiprocessor(&maxb, (const void*)fused_head,
                                                     256, 0);
  const bool use_coop = (coop != 0) && ((long)maxb * (long)ncu >= NBLK_C);

  if (use_coop) {
    void* args[] = {(void*)&x, (void*)&Wq, (void*)&Wk, (void*)&Wv,
                    (void*)&qkv, (void*)&WT, (void*)&Opart, (void*)&lpart,
                    (void*)&out};
    hipLaunchCooperativeKernel((void*)fused_head, dim3(NBLK_C), dim3(256), args,
                               0, stream);
  } else {
    prep_w<<<384, 256, 0, stream>>>(Wq, Wk, Wv, WT);
    qkv_proj<<<dim3(BB * SS / 32, 3), 256, 0, stream>>>(x, WT, qkv);
    flash_attn_mfma<<<BB * AUNITS, 256, 0, stream>>>(qkv, out, Opart, lpart);
    attn_merge<<<BB * 30 * 4, 256, 0, stream>>>(Opart, lpart, out);
  }
}